// Round 3
// baseline (429.459 us; speedup 1.0000x reference)
//
#include <hip/hip_runtime.h>
#include <stdint.h>

#define D_IN  4096
#define D_OUT 4096
#define M_TOT 8192      // B*S = 4*2048

#define BM 128
#define BN 128
#define BK 64

using i32x4 = __attribute__((ext_vector_type(4))) int;

// ---------------------------------------------------------------------------
// Fused prep kernel.
//   blocks [0, M_TOT):             per-row activation fake-quant -> xq, s
//   blocks [M_TOT, M_TOT+16384):   pack int32-widened weight -> int8
// Both jobs are BW-bound; fusing lets them share the GPU in one launch.
// ---------------------------------------------------------------------------
__global__ __launch_bounds__(256) void prep(
    const float* __restrict__ x, int8_t* __restrict__ xq,
    float* __restrict__ s_out,
    const int* __restrict__ w32, int8_t* __restrict__ w8)
{
    const int tid = threadIdx.x;
    const int b   = blockIdx.x;

    if (b < M_TOT) {
        // ---- quantize one activation row of 4096 fp32 ----
        __shared__ float wmax[4];
        const float* xr = x + (size_t)b * D_IN;

        float4 v[4];
        float m = 0.f;
#pragma unroll
        for (int c = 0; c < 4; ++c) {
            v[c] = ((const float4*)xr)[c * 256 + tid];
            m = fmaxf(m, fmaxf(fmaxf(fabsf(v[c].x), fabsf(v[c].y)),
                               fmaxf(fabsf(v[c].z), fabsf(v[c].w))));
        }
#pragma unroll
        for (int off = 1; off < 64; off <<= 1)
            m = fmaxf(m, __shfl_xor(m, off));
        if ((tid & 63) == 0) wmax[tid >> 6] = m;
        __syncthreads();
        m = fmaxf(fmaxf(wmax[0], wmax[1]), fmaxf(wmax[2], wmax[3]));

        const float s   = m / 127.0f + 1e-8f;  // matches reference arithmetic
        const float inv = 1.0f / s;            // one precise div; then mul
        if (tid == 0) s_out[b] = s;

        int* q32 = (int*)(xq + (size_t)b * D_IN);
#pragma unroll
        for (int c = 0; c < 4; ++c) {
            int q0 = (int)rintf(v[c].x * inv);   // round-half-even = jnp.round
            int q1 = (int)rintf(v[c].y * inv);
            int q2 = (int)rintf(v[c].z * inv);
            int q3 = (int)rintf(v[c].w * inv);
            q32[c * 256 + tid] = (q0 & 0xff) | ((q1 & 0xff) << 8) |
                                 ((q2 & 0xff) << 16) | ((q3 & 0xff) << 24);
        }
    } else {
        // ---- pack weight: 4 int32 -> 4 int8 bytes ----
        const int i = (b - M_TOT) * 256 + tid;   // [0, 4M)
        int4 v = ((const int4*)w32)[i];
        ((int*)w8)[i] = (v.x & 0xff) | ((v.y & 0xff) << 8) |
                        ((v.z & 0xff) << 16) | ((v.w & 0xff) << 24);
    }
}

// ---------------------------------------------------------------------------
// int8 GEMM  Y[M][N] = (qx[M][K] . qw[N][K]^T) * (s[m]*wscale) + bias
// 128x128 tile, BK=64, 4 waves (2x2), mfma_i32_16x16x64_i8.
// m97 structure + T1 XCD-aware block swizzle (grid 2048 = 8*256, divisible).
// ---------------------------------------------------------------------------
__device__ __forceinline__ void gload_lds16(const void* g, void* l) {
    __builtin_amdgcn_global_load_lds(
        (const __attribute__((address_space(1))) unsigned int*)(uintptr_t)g,
        (__attribute__((address_space(3))) unsigned int*)(uintptr_t)l,
        16, 0, 0);
}

__global__ __launch_bounds__(256) void gemm_i8(
    const int8_t* __restrict__ Aq, const int8_t* __restrict__ Wq,
    const float* __restrict__ srow, const float* __restrict__ wsc,
    const float* __restrict__ bias, float* __restrict__ Y)
{
    __shared__ int8_t lA[BM * BK];   // 8 KiB
    __shared__ int8_t lB[BN * BK];   // 8 KiB

    const int tid  = threadIdx.x;
    const int lane = tid & 63;
    const int wave = tid >> 6;

    // T1: XCD-aware swizzle. nwg = 2048, 8 XCDs -> 256 contiguous blocks/XCD.
    const int b    = blockIdx.x;
    const int swz  = (b & 7) * 256 + (b >> 3);
    const int nbx  = D_OUT / BN;                 // 32
    const int bn   = (swz % nbx) * BN;
    const int bm   = (swz / nbx) * BM;

    const int wr   = (wave >> 1) * 64;           // wave sub-tile origin (rows)
    const int wc   = (wave & 1) * 64;            // wave sub-tile origin (cols)

    i32x4 acc[4][4] = {};

    const int fr = lane & 15;
    const int fk = (lane >> 4) * 16;

    const int8_t* gA = Aq + (size_t)bm * D_IN;
    const int8_t* gW = Wq + (size_t)bn * D_IN;

    for (int kt = 0; kt < D_IN; kt += BK) {
        // stage A and B tiles: 512 chunks of 16B each, 2 per thread per tile.
        // LDS dest linear in chunk index = wave-uniform base + lane*16.
#pragma unroll
        for (int j = 0; j < 2; ++j) {
            const int c  = j * 256 + tid;
            const int r  = c >> 2;
            const int ko = (c & 3) * 16;
            gload_lds16(gA + (size_t)r * D_IN + kt + ko, lA + c * 16);
            gload_lds16(gW + (size_t)r * D_IN + kt + ko, lB + c * 16);
        }
        __syncthreads();   // compiler drains vmcnt before barrier

        i32x4 a[4], bfr[4];
#pragma unroll
        for (int i = 0; i < 4; ++i) {
            a[i]   = *(const i32x4*)(lA + (wr + i * 16 + fr) * BK + fk);
            bfr[i] = *(const i32x4*)(lB + (wc + i * 16 + fr) * BK + fk);
        }
#pragma unroll
        for (int i = 0; i < 4; ++i)
#pragma unroll
            for (int j = 0; j < 4; ++j)
                acc[i][j] = __builtin_amdgcn_mfma_i32_16x16x64_i8(
                    a[i], bfr[j], acc[i][j], 0, 0, 0);
        __syncthreads();
    }

    // Epilogue: y = acc * (s[m]*wscale) + bias[n]
    // C/D layout: col = lane&15, row = (lane>>4)*4 + reg (dtype-independent)
    const float ws = wsc[0];
    float bs[4];
#pragma unroll
    for (int j = 0; j < 4; ++j) bs[j] = bias[bn + wc + j * 16 + fr];

#pragma unroll
    for (int i = 0; i < 4; ++i) {
        const int m0 = bm + wr + i * 16 + (lane >> 4) * 4;
#pragma unroll
        for (int r = 0; r < 4; ++r) {
            const float sm = srow[m0 + r] * ws;
            float* yp = Y + (size_t)(m0 + r) * D_OUT + bn + wc + fr;
#pragma unroll
            for (int j = 0; j < 4; ++j)
                yp[j * 16] = (float)acc[i][j][r] * sm + bs[j];
        }
    }
}

// ---------------------------------------------------------------------------
extern "C" void kernel_launch(void* const* d_in, const int* in_sizes, int n_in,
                              void* d_out, int out_size, void* d_ws, size_t ws_size,
                              hipStream_t stream) {
    const float* x    = (const float*)d_in[0];
    const int*   w32  = (const int*)d_in[1];     // int8 values widened to int32
    const float* wsc  = (const float*)d_in[2];
    const float* bias = (const float*)d_in[3];
    float* y = (float*)d_out;

    // workspace layout: qx (32 MiB) | w8 (16 MiB) | s (32 KiB)
    int8_t* xq = (int8_t*)d_ws;
    int8_t* w8 = xq + (size_t)M_TOT * D_IN;
    float*  s  = (float*)(w8 + (size_t)D_OUT * D_IN);

    const int pack_blocks = (D_OUT * D_IN / 4) / 256;   // 16384
    prep<<<M_TOT + pack_blocks, 256, 0, stream>>>(x, xq, s, w32, w8);

    gemm_i8<<<(M_TOT / BM) * (D_OUT / BN), 256, 0, stream>>>(xq, w8, s, wsc, bias, y);
}

// Round 5
// 427.083 us; speedup vs baseline: 1.0056x; 1.0056x over previous
//
#include <hip/hip_runtime.h>
#include <stdint.h>

#define D_IN  4096
#define D_OUT 4096
#define M_TOT 8192      // B*S = 4*2048

#define BM 128
#define BN 128
#define BK 64           // int8 elements = 64 bytes/row (same byte layout as m97 bf16 BK=32)

using i32x4 = __attribute__((ext_vector_type(4))) int;

// ---------------------------------------------------------------------------
// Fused prep kernel.
//   blocks [0, M_TOT):             per-row activation fake-quant -> xq, s
//   blocks [M_TOT, M_TOT+16384):   pack int32-widened weight -> int8
// ---------------------------------------------------------------------------
__global__ __launch_bounds__(256) void prep(
    const float* __restrict__ x, int8_t* __restrict__ xq,
    float* __restrict__ s_out,
    const int* __restrict__ w32, int8_t* __restrict__ w8)
{
    const int tid = threadIdx.x;
    const int b   = blockIdx.x;

    if (b < M_TOT) {
        // ---- quantize one activation row of 4096 fp32 ----
        __shared__ float wmax[4];
        const float* xr = x + (size_t)b * D_IN;

        float4 v[4];
        float m = 0.f;
#pragma unroll
        for (int c = 0; c < 4; ++c) {
            v[c] = ((const float4*)xr)[c * 256 + tid];
            m = fmaxf(m, fmaxf(fmaxf(fabsf(v[c].x), fabsf(v[c].y)),
                               fmaxf(fabsf(v[c].z), fabsf(v[c].w))));
        }
#pragma unroll
        for (int off = 1; off < 64; off <<= 1)
            m = fmaxf(m, __shfl_xor(m, off));
        if ((tid & 63) == 0) wmax[tid >> 6] = m;
        __syncthreads();
        m = fmaxf(fmaxf(wmax[0], wmax[1]), fmaxf(wmax[2], wmax[3]));

        const float s   = m / 127.0f + 1e-8f;  // matches reference arithmetic
        const float inv = 1.0f / s;            // one precise div; then mul
        if (tid == 0) s_out[b] = s;

        int* q32 = (int*)(xq + (size_t)b * D_IN);
#pragma unroll
        for (int c = 0; c < 4; ++c) {
            int q0 = (int)rintf(v[c].x * inv);   // round-half-even = jnp.round
            int q1 = (int)rintf(v[c].y * inv);
            int q2 = (int)rintf(v[c].z * inv);
            int q3 = (int)rintf(v[c].w * inv);
            q32[c * 256 + tid] = (q0 & 0xff) | ((q1 & 0xff) << 8) |
                                 ((q2 & 0xff) << 16) | ((q3 & 0xff) << 24);
        }
    } else {
        // ---- pack weight: 4 int32 -> 4 int8 bytes ----
        const int i = (b - M_TOT) * 256 + tid;   // [0, 4M)
        int4 v = ((const int4*)w32)[i];
        ((int*)w8)[i] = (v.x & 0xff) | ((v.y & 0xff) << 8) |
                        ((v.z & 0xff) << 16) | ((v.w & 0xff) << 24);
    }
}

// ---------------------------------------------------------------------------
// int8 GEMM  Y[M][N] = (qx[M][K] . qw[N][K]^T) * (s[m]*wscale) + bias
// 128x128 tile, BK=64, 4 waves (2x2), mfma_i32_16x16x64_i8.
// T3-minimum double-buffered 2-phase: STAGE(t+1) issued before compute(t);
// single __syncthreads()/K-step so the vmcnt drain lands AFTER the MFMAs.
// No blockIdx swizzle (T1 regressed 10% here: working set is L3-resident).
// ---------------------------------------------------------------------------
__device__ __forceinline__ void gload_lds16(const void* g, void* l) {
    __builtin_amdgcn_global_load_lds(
        (const __attribute__((address_space(1))) unsigned int*)(uintptr_t)g,
        (__attribute__((address_space(3))) unsigned int*)(uintptr_t)l,
        16, 0, 0);
}

__global__ __launch_bounds__(256) void gemm_i8(
    const int8_t* __restrict__ Aq, const int8_t* __restrict__ Wq,
    const float* __restrict__ srow, const float* __restrict__ wsc,
    const float* __restrict__ bias, float* __restrict__ Y)
{
    __shared__ int8_t lA[2][BM * BK];   // 2 x 8 KiB
    __shared__ int8_t lB[2][BN * BK];   // 2 x 8 KiB

    const int tid  = threadIdx.x;
    const int lane = tid & 63;
    const int wave = tid >> 6;
    const int nbx  = D_OUT / BN;                 // 32
    const int bn   = ((int)blockIdx.x % nbx) * BN;
    const int bm   = ((int)blockIdx.x / nbx) * BM;

    const int wr   = (wave >> 1) * 64;           // wave sub-tile origin (rows)
    const int wc   = (wave & 1) * 64;            // wave sub-tile origin (cols)

    i32x4 acc[4][4] = {};

    const int fr = lane & 15;
    const int fk = (lane >> 4) * 16;

    const int8_t* gA = Aq + (size_t)bm * D_IN;
    const int8_t* gW = Wq + (size_t)bn * D_IN;

    // Stage one 128x64B A-tile + B-tile into buffer `buf` for K-offset kt.
    // 512 chunks of 16B per matrix, 2 per thread; LDS dest linear in chunk idx.
#define STAGE(buf, kt)                                                        \
    {                                                                         \
        _Pragma("unroll")                                                     \
        for (int j = 0; j < 2; ++j) {                                         \
            const int c  = j * 256 + tid;                                     \
            const int r  = c >> 2;                                            \
            const int ko = (c & 3) * 16;                                      \
            gload_lds16(gA + (size_t)r * D_IN + (kt) + ko, &lA[buf][c * 16]); \
            gload_lds16(gW + (size_t)r * D_IN + (kt) + ko, &lB[buf][c * 16]); \
        }                                                                     \
    }

#define COMPUTE(buf)                                                          \
    {                                                                         \
        i32x4 a[4], bfr[4];                                                   \
        _Pragma("unroll")                                                     \
        for (int i = 0; i < 4; ++i) {                                         \
            a[i]   = *(const i32x4*)(&lA[buf][(wr + i * 16 + fr) * BK + fk]); \
            bfr[i] = *(const i32x4*)(&lB[buf][(wc + i * 16 + fr) * BK + fk]); \
        }                                                                     \
        _Pragma("unroll")                                                     \
        for (int i = 0; i < 4; ++i)                                           \
            _Pragma("unroll")                                                 \
            for (int j = 0; j < 4; ++j)                                       \
                acc[i][j] = __builtin_amdgcn_mfma_i32_16x16x64_i8(            \
                    a[i], bfr[j], acc[i][j], 0, 0, 0);                        \
    }

    const int NT = D_IN / BK;   // 64 K-tiles

    // prologue: stage tile 0, drain, enter loop
    STAGE(0, 0);
    __syncthreads();

    int cur = 0;
    for (int t = 0; t < NT - 1; ++t) {
        STAGE(cur ^ 1, (t + 1) * BK);   // issue next-tile loads (in flight
                                        // across the MFMAs below)
        COMPUTE(cur);                   // ds_read + 16 MFMA on current buffer
        __syncthreads();                // drains vmcnt(0): next buffer ready,
                                        // all waves done reading buf[cur]
        cur ^= 1;
    }
    COMPUTE(cur);                       // epilogue tile, no prefetch
#undef STAGE
#undef COMPUTE

    // Epilogue: y = acc * (s[m]*wscale) + bias[n]
    // C/D layout: col = lane&15, row = (lane>>4)*4 + reg (dtype-independent)
    const float ws = wsc[0];
    float bs[4];
#pragma unroll
    for (int j = 0; j < 4; ++j) bs[j] = bias[bn + wc + j * 16 + fr];

#pragma unroll
    for (int i = 0; i < 4; ++i) {
        const int m0 = bm + wr + i * 16 + (lane >> 4) * 4;
#pragma unroll
        for (int r = 0; r < 4; ++r) {
            const float sm = srow[m0 + r] * ws;
            float* yp = Y + (size_t)(m0 + r) * D_OUT + bn + wc + fr;
#pragma unroll
            for (int j = 0; j < 4; ++j)
                yp[j * 16] = (float)acc[i][j][r] * sm + bs[j];
        }
    }
}

// ---------------------------------------------------------------------------
extern "C" void kernel_launch(void* const* d_in, const int* in_sizes, int n_in,
                              void* d_out, int out_size, void* d_ws, size_t ws_size,
                              hipStream_t stream) {
    const float* x    = (const float*)d_in[0];
    const int*   w32  = (const int*)d_in[1];     // int8 values widened to int32
    const float* wsc  = (const float*)d_in[2];
    const float* bias = (const float*)d_in[3];
    float* y = (float*)d_out;

    // workspace layout: qx (32 MiB) | w8 (16 MiB) | s (32 KiB)
    int8_t* xq = (int8_t*)d_ws;
    int8_t* w8 = xq + (size_t)M_TOT * D_IN;
    float*  s  = (float*)(w8 + (size_t)D_OUT * D_IN);

    const int pack_blocks = (D_OUT * D_IN / 4) / 256;   // 16384
    prep<<<M_TOT + pack_blocks, 256, 0, stream>>>(x, xq, s, w32, w8);

    gemm_i8<<<(M_TOT / BM) * (D_OUT / BN), 256, 0, stream>>>(xq, w8, s, wsc, bias, y);
}

// Round 7
// 392.696 us; speedup vs baseline: 1.0936x; 1.0876x over previous
//
#include <hip/hip_runtime.h>
#include <stdint.h>

#define D_IN  4096
#define D_OUT 4096
#define M_TOT 8192      // B*S = 4*2048

#define BM 256
#define BN 256
#define BKB 128         // K-step in int8 elements (=bytes); 2 MFMA-K per step
#define NT (D_IN / BKB) // 32 K-tiles

using i32x4 = __attribute__((ext_vector_type(4))) int;

// ---------------------------------------------------------------------------
// Fused prep kernel (unchanged from round 5).
//   blocks [0, M_TOT):             per-row activation fake-quant -> xq, s
//   blocks [M_TOT, M_TOT+16384):   pack int32-widened weight -> int8
// ---------------------------------------------------------------------------
__global__ __launch_bounds__(256) void prep(
    const float* __restrict__ x, int8_t* __restrict__ xq,
    float* __restrict__ s_out,
    const int* __restrict__ w32, int8_t* __restrict__ w8)
{
    const int tid = threadIdx.x;
    const int b   = blockIdx.x;

    if (b < M_TOT) {
        __shared__ float wmax[4];
        const float* xr = x + (size_t)b * D_IN;

        float4 v[4];
        float m = 0.f;
#pragma unroll
        for (int c = 0; c < 4; ++c) {
            v[c] = ((const float4*)xr)[c * 256 + tid];
            m = fmaxf(m, fmaxf(fmaxf(fabsf(v[c].x), fabsf(v[c].y)),
                               fmaxf(fabsf(v[c].z), fabsf(v[c].w))));
        }
#pragma unroll
        for (int off = 1; off < 64; off <<= 1)
            m = fmaxf(m, __shfl_xor(m, off));
        if ((tid & 63) == 0) wmax[tid >> 6] = m;
        __syncthreads();
        m = fmaxf(fmaxf(wmax[0], wmax[1]), fmaxf(wmax[2], wmax[3]));

        const float s   = m / 127.0f + 1e-8f;  // matches reference arithmetic
        const float inv = 1.0f / s;
        if (tid == 0) s_out[b] = s;

        int* q32 = (int*)(xq + (size_t)b * D_IN);
#pragma unroll
        for (int c = 0; c < 4; ++c) {
            int q0 = (int)rintf(v[c].x * inv);   // round-half-even = jnp.round
            int q1 = (int)rintf(v[c].y * inv);
            int q2 = (int)rintf(v[c].z * inv);
            int q3 = (int)rintf(v[c].w * inv);
            q32[c * 256 + tid] = (q0 & 0xff) | ((q1 & 0xff) << 8) |
                                 ((q2 & 0xff) << 16) | ((q3 & 0xff) << 24);
        }
    } else {
        const int i = (b - M_TOT) * 256 + tid;
        int4 v = ((const int4*)w32)[i];
        ((int*)w8)[i] = (v.x & 0xff) | ((v.y & 0xff) << 8) |
                        ((v.z & 0xff) << 16) | ((v.w & 0xff) << 24);
    }
}

// ---------------------------------------------------------------------------
// 8-phase int8 GEMM (T2+T3+T4+T5 port of the 256^2 template).
//   Y[M][N] = (qx . qw^T) * (s[m]*wscale) + bias[n]
// 256x256 tile, BK=128 B, 8 waves (2Mx4N), 512 thr, 128 KiB LDS (2-tile dbuf).
//
// LDS layout per matrix (A at 0, B at 65536):
//   buf b at b*32768; K-half kh at kh*16384; row r (0..255) at r*64;
//   16B chunk g stored at g ^ ((r>>1)&3)  [T2: exactly 2 lanes/bank = free]
// Staged via global_load_lds with LINEAR dest + inverse-swizzled SOURCE
// (rule #21; XOR is an involution).
//
// Half-tile unit = one matrix x one K-half = 16 KiB = 2 loads/thread.
// Phases of tile t (buf = t&1): p1/p2 compute K-lo (frag rows 0-3 / 4-7),
// p3/p4 compute K-hi.  Stage issue: AKhi(t+1)@p1, BKhi(t+1)@p2,
// AKlo(t+2)@p3, BKlo(t+2)@p4.
//
// vmcnt discipline (per wave, 2 instr/half; verified exact):
//  - end p2: need Khi(t) landed; issued-after = {AKlo(t+1),BKlo(t+1),
//    AKhi(t+1),BKhi(t+1)} = 8 instr -> vmcnt(8).
//  - end p4: need Klo(t+1) landed; issued-after = 4 halves -> vmcnt(8).
//  - tail: tile30 p4 -> vmcnt(4); tile31 p2 -> vmcnt(0).
// Race-freedom: every in-flight load targets a region whose last reader
// finished before the issue point and whose next reader is behind the
// covering vmcnt+barrier.
// ---------------------------------------------------------------------------
__device__ __forceinline__ void gload_lds16(const void* g, void* l) {
    __builtin_amdgcn_global_load_lds(
        (const __attribute__((address_space(1))) unsigned int*)(uintptr_t)g,
        (__attribute__((address_space(3))) unsigned int*)(uintptr_t)l,
        16, 0, 0);
}

__global__ __launch_bounds__(512, 2) void gemm_i8(
    const int8_t* __restrict__ Aq, const int8_t* __restrict__ Wq,
    const float* __restrict__ srow, const float* __restrict__ wsc,
    const float* __restrict__ bias, float* __restrict__ Y)
{
    __shared__ int8_t lds[131072];   // 128 KiB: A[2][2][256][64] | B[...]

    const int tid  = threadIdx.x;
    const int lane = tid & 63;
    const int wave = tid >> 6;
    const int nbx  = D_OUT / BN;            // 16
    const int bn   = ((int)blockIdx.x % nbx) * BN;
    const int bm   = ((int)blockIdx.x / nbx) * BM;
    const int wr   = wave >> 2;             // 0..1  (128-row block)
    const int wc   = wave & 3;              // 0..3  (64-col block)
    const int fr   = lane & 15;
    const int gk   = lane >> 4;             // 0..3 (16B k-chunk)

    i32x4 acc[8][4] = {};

    const int8_t* gA = Aq + (size_t)bm * D_IN;
    const int8_t* gB = Wq + (size_t)bn * D_IN;

    // Stage one half-tile (1024 chunks of 16B; thread -> chunks tid, tid+512,
    // wave-linear so the LDS dest is base+lane*16). Source pre-swizzled.
#define STAGE_HALF(gbase, kt, kh, lofs)                                        \
    {                                                                          \
        _Pragma("unroll")                                                      \
        for (int u = 0; u < 2; ++u) {                                         \
            const int c_   = u * 512 + tid;                                   \
            const int row_ = c_ >> 2;                                         \
            const int gs_  = (c_ & 3) ^ ((row_ >> 1) & 3);                    \
            gload_lds16(gbase + (size_t)row_ * D_IN + (kt) + (kh) * 64        \
                              + gs_ * 16,                                     \
                        lds + (lofs) + (kh) * 16384 + c_ * 16);               \
        }                                                                      \
    }

#define VM8  asm volatile("s_waitcnt vmcnt(8)" ::: "memory")
#define VM4  asm volatile("s_waitcnt vmcnt(4)" ::: "memory")
#define VM0  asm volatile("s_waitcnt vmcnt(0)" ::: "memory")
#define NOWAIT
#define NOSTAGE

    // One phase: 8x ds_read_b128 (swizzled) || stage issue || barrier ||
    // 16 MFMA under setprio || [vmcnt] || barrier.
#define PHASE(bufA, bufB, fh, kh, STAGE_STMT, WAIT_STMT)                       \
    {                                                                          \
        i32x4 a_[4], b_[4];                                                    \
        _Pragma("unroll")                                                      \
        for (int i = 0; i < 4; ++i) {                                         \
            const int ra_ = wr * 128 + (fh) * 64 + i * 16 + fr;               \
            a_[i] = *(const i32x4*)(lds + (bufA) + (kh) * 16384 + ra_ * 64    \
                                    + ((gk ^ ((ra_ >> 1) & 3)) * 16));        \
            const int rb_ = wc * 64 + i * 16 + fr;                            \
            b_[i] = *(const i32x4*)(lds + (bufB) + (kh) * 16384 + rb_ * 64    \
                                    + ((gk ^ ((rb_ >> 1) & 3)) * 16));        \
        }                                                                      \
        STAGE_STMT;                                                            \
        __builtin_amdgcn_s_barrier();                                          \
        __builtin_amdgcn_s_setprio(1);                                         \
        _Pragma("unroll")                                                      \
        for (int i = 0; i < 4; ++i)                                           \
            _Pragma("unroll")                                                  \
            for (int j = 0; j < 4; ++j)                                       \
                acc[(fh) * 4 + i][j] = __builtin_amdgcn_mfma_i32_16x16x64_i8( \
                    a_[i], b_[j], acc[(fh) * 4 + i][j], 0, 0, 0);             \
        __builtin_amdgcn_s_setprio(0);                                         \
        WAIT_STMT;                                                             \
        __builtin_amdgcn_s_barrier();                                          \
    }

#define KTILE(buf, S1, S2, S3, S4, W2, W4)                                     \
    PHASE((buf) * 32768, 65536 + (buf) * 32768, 0, 0, S1, NOWAIT);            \
    PHASE((buf) * 32768, 65536 + (buf) * 32768, 1, 0, S2, W2);                \
    PHASE((buf) * 32768, 65536 + (buf) * 32768, 0, 1, S3, NOWAIT);            \
    PHASE((buf) * 32768, 65536 + (buf) * 32768, 1, 1, S4, W4);

    // ---- prologue: Klo(0),Khi(0) -> buf0; Klo(1) -> buf1; ensure tile 0 ----
    STAGE_HALF(gA, 0,   0, 0);
    STAGE_HALF(gB, 0,   0, 65536);
    STAGE_HALF(gA, 0,   1, 0);
    STAGE_HALF(gB, 0,   1, 65536);
    STAGE_HALF(gA, BKB, 0, 32768);
    STAGE_HALF(gB, BKB, 0, 65536 + 32768);
    VM4;                                   // allow Klo(1) pair outstanding
    __builtin_amdgcn_s_barrier();

    // ---- main loop: tiles 0..29, static buffer parity ----
    for (int t = 0; t < NT - 2; t += 2) {
        KTILE(0,
              STAGE_HALF(gA, (t + 1) * BKB, 1, 32768),
              STAGE_HALF(gB, (t + 1) * BKB, 1, 65536 + 32768),
              STAGE_HALF(gA, (t + 2) * BKB, 0, 0),
              STAGE_HALF(gB, (t + 2) * BKB, 0, 65536),
              VM8, VM8);
        KTILE(1,
              STAGE_HALF(gA, (t + 2) * BKB, 1, 0),
              STAGE_HALF(gB, (t + 2) * BKB, 1, 65536),
              STAGE_HALF(gA, (t + 3) * BKB, 0, 32768),
              STAGE_HALF(gB, (t + 3) * BKB, 0, 65536 + 32768),
              VM8, VM8);
    }
    // ---- tile 30 (buf0): stage only Khi(31) -> buf1 ----
    KTILE(0,
          STAGE_HALF(gA, 31 * BKB, 1, 32768),
          STAGE_HALF(gB, 31 * BKB, 1, 65536 + 32768),
          NOSTAGE, NOSTAGE,
          VM8, VM4);
    // ---- tile 31 (buf1): no stages; drain Khi(31) before p3 ----
    KTILE(1, NOSTAGE, NOSTAGE, NOSTAGE, NOSTAGE, VM0, NOWAIT);

#undef KTILE
#undef PHASE
#undef STAGE_HALF

    // ---- epilogue: y = acc * (s[m]*wscale) + bias[n] ----
    // C/D layout: col = lane&15, row = (lane>>4)*4 + reg (dtype-independent)
    const float ws = wsc[0];
    float bs[4];
#pragma unroll
    for (int j = 0; j < 4; ++j) bs[j] = bias[bn + wc * 64 + j * 16 + fr];

#pragma unroll
    for (int i = 0; i < 8; ++i) {
        const int m0 = bm + wr * 128 + i * 16 + gk * 4;
#pragma unroll
        for (int r = 0; r < 4; ++r) {
            const float sm = srow[m0 + r] * ws;
            float* yp = Y + (size_t)(m0 + r) * D_OUT + bn + wc * 64 + fr;
#pragma unroll
            for (int j = 0; j < 4; ++j)
                yp[j * 16] = (float)acc[i][j][r] * sm + bs[j];
        }
    }
}

// ---------------------------------------------------------------------------
extern "C" void kernel_launch(void* const* d_in, const int* in_sizes, int n_in,
                              void* d_out, int out_size, void* d_ws, size_t ws_size,
                              hipStream_t stream) {
    const float* x    = (const float*)d_in[0];
    const int*   w32  = (const int*)d_in[1];     // int8 values widened to int32
    const float* wsc  = (const float*)d_in[2];
    const float* bias = (const float*)d_in[3];
    float* y = (float*)d_out;

    // workspace layout: qx (32 MiB) | w8 (16 MiB) | s (32 KiB)
    int8_t* xq = (int8_t*)d_ws;
    int8_t* w8 = xq + (size_t)M_TOT * D_IN;
    float*  s  = (float*)(w8 + (size_t)D_OUT * D_IN);

    const int pack_blocks = (D_OUT * D_IN / 4) / 256;   // 16384
    prep<<<M_TOT + pack_blocks, 256, 0, stream>>>(x, xq, s, w32, w8);

    gemm_i8<<<(M_TOT / BM) * (D_OUT / BN), 512, 0, stream>>>(xq, w8, s, wsc, bias, y);
}

// Round 8
// 384.545 us; speedup vs baseline: 1.1168x; 1.0212x over previous
//
#include <hip/hip_runtime.h>
#include <stdint.h>

#define D_IN  4096
#define D_OUT 4096
#define M_TOT 8192      // B*S = 4*2048

#define BM 256
#define BN 256
#define BKB 128         // K-step in int8 elements (=bytes); 2 MFMA-K per step
#define NT (D_IN / BKB) // 32 K-tiles

using i32x4 = __attribute__((ext_vector_type(4))) int;

// ---------------------------------------------------------------------------
// Fused prep kernel (unchanged).
//   blocks [0, M_TOT):             per-row activation fake-quant -> xq, s
//   blocks [M_TOT, M_TOT+16384):   pack int32-widened weight -> int8
// ---------------------------------------------------------------------------
__global__ __launch_bounds__(256) void prep(
    const float* __restrict__ x, int8_t* __restrict__ xq,
    float* __restrict__ s_out,
    const int* __restrict__ w32, int8_t* __restrict__ w8)
{
    const int tid = threadIdx.x;
    const int b   = blockIdx.x;

    if (b < M_TOT) {
        __shared__ float wmax[4];
        const float* xr = x + (size_t)b * D_IN;

        float4 v[4];
        float m = 0.f;
#pragma unroll
        for (int c = 0; c < 4; ++c) {
            v[c] = ((const float4*)xr)[c * 256 + tid];
            m = fmaxf(m, fmaxf(fmaxf(fabsf(v[c].x), fabsf(v[c].y)),
                               fmaxf(fabsf(v[c].z), fabsf(v[c].w))));
        }
#pragma unroll
        for (int off = 1; off < 64; off <<= 1)
            m = fmaxf(m, __shfl_xor(m, off));
        if ((tid & 63) == 0) wmax[tid >> 6] = m;
        __syncthreads();
        m = fmaxf(fmaxf(wmax[0], wmax[1]), fmaxf(wmax[2], wmax[3]));

        const float s   = m / 127.0f + 1e-8f;  // matches reference arithmetic
        const float inv = 1.0f / s;
        if (tid == 0) s_out[b] = s;

        int* q32 = (int*)(xq + (size_t)b * D_IN);
#pragma unroll
        for (int c = 0; c < 4; ++c) {
            int q0 = (int)rintf(v[c].x * inv);   // round-half-even = jnp.round
            int q1 = (int)rintf(v[c].y * inv);
            int q2 = (int)rintf(v[c].z * inv);
            int q3 = (int)rintf(v[c].w * inv);
            q32[c * 256 + tid] = (q0 & 0xff) | ((q1 & 0xff) << 8) |
                                 ((q2 & 0xff) << 16) | ((q3 & 0xff) << 24);
        }
    } else {
        const int i = (b - M_TOT) * 256 + tid;
        int4 v = ((const int4*)w32)[i];
        ((int*)w8)[i] = (v.x & 0xff) | ((v.y & 0xff) << 8) |
                        ((v.z & 0xff) << 16) | ((v.w & 0xff) << 24);
    }
}

// ---------------------------------------------------------------------------
// 8-phase int8 GEMM (T2+T3+T4+T5).  NEW this round: B-fragment register
// reuse across fh-pairs (PHASE_AB reads A+B, PHASE_A reads A only) —
// 24 instead of 32 ds_read_b128 per wave per K-tile (-25% LDS-read traffic,
// matching the m201 template's asymmetric 4-or-8-reads-per-phase shape).
//
// LDS layout per matrix (A at 0, B at 65536):
//   buf b at b*32768; K-half kh at kh*16384; row r (0..255) at r*64;
//   16B chunk g stored at g ^ ((r>>1)&3)  [T2: exactly 2 lanes/bank = free]
// Staged via global_load_lds with LINEAR dest + inverse-swizzled SOURCE.
//
// Phases of tile t (buf = t&1): p1/p2 compute K-lo, p3/p4 K-hi.
// Stage issue: AKhi(t+1)@p1, BKhi(t+1)@p2, AKlo(t+2)@p3, BKlo(t+2)@p4.
// vmcnt (2 instr/half; exact): end p2 -> vmcnt(8) [Khi(t) landed];
// end p4 -> vmcnt(8) [Klo(t+1) landed]; tail: vmcnt(4), vmcnt(0).
// ---------------------------------------------------------------------------
__device__ __forceinline__ void gload_lds16(const void* g, void* l) {
    __builtin_amdgcn_global_load_lds(
        (const __attribute__((address_space(1))) unsigned int*)(uintptr_t)g,
        (__attribute__((address_space(3))) unsigned int*)(uintptr_t)l,
        16, 0, 0);
}

__global__ __launch_bounds__(512, 2) void gemm_i8(
    const int8_t* __restrict__ Aq, const int8_t* __restrict__ Wq,
    const float* __restrict__ srow, const float* __restrict__ wsc,
    const float* __restrict__ bias, float* __restrict__ Y)
{
    __shared__ int8_t lds[131072];   // 128 KiB: A[2][2][256][64] | B[...]

    const int tid  = threadIdx.x;
    const int lane = tid & 63;
    const int wave = tid >> 6;
    const int nbx  = D_OUT / BN;            // 16
    const int bn   = ((int)blockIdx.x % nbx) * BN;
    const int bm   = ((int)blockIdx.x / nbx) * BM;
    const int wr   = wave >> 2;             // 0..1  (128-row block)
    const int wc   = wave & 3;              // 0..3  (64-col block)
    const int fr   = lane & 15;
    const int gk   = lane >> 4;             // 0..3 (16B k-chunk)

    i32x4 acc[8][4] = {};
    i32x4 bfrag[4];                         // B fragments, live across fh-pair

    const int8_t* gA = Aq + (size_t)bm * D_IN;
    const int8_t* gB = Wq + (size_t)bn * D_IN;

#define STAGE_HALF(gbase, kt, kh, lofs)                                        \
    {                                                                          \
        _Pragma("unroll")                                                      \
        for (int u = 0; u < 2; ++u) {                                         \
            const int c_   = u * 512 + tid;                                   \
            const int row_ = c_ >> 2;                                         \
            const int gs_  = (c_ & 3) ^ ((row_ >> 1) & 3);                    \
            gload_lds16(gbase + (size_t)row_ * D_IN + (kt) + (kh) * 64        \
                              + gs_ * 16,                                     \
                        lds + (lofs) + (kh) * 16384 + c_ * 16);               \
        }                                                                      \
    }

#define VM8  asm volatile("s_waitcnt vmcnt(8)" ::: "memory")
#define VM4  asm volatile("s_waitcnt vmcnt(4)" ::: "memory")
#define VM0  asm volatile("s_waitcnt vmcnt(0)" ::: "memory")
#define NOWAIT
#define NOSTAGE

#define READ_A(bufA, fh, kh)                                                   \
        _Pragma("unroll")                                                      \
        for (int i = 0; i < 4; ++i) {                                         \
            const int ra_ = wr * 128 + (fh) * 64 + i * 16 + fr;               \
            a_[i] = *(const i32x4*)(lds + (bufA) + (kh) * 16384 + ra_ * 64    \
                                    + ((gk ^ ((ra_ >> 1) & 3)) * 16));        \
        }

#define READ_B(bufB, kh)                                                       \
        _Pragma("unroll")                                                      \
        for (int i = 0; i < 4; ++i) {                                         \
            const int rb_ = wc * 64 + i * 16 + fr;                            \
            bfrag[i] = *(const i32x4*)(lds + (bufB) + (kh) * 16384 + rb_ * 64 \
                                    + ((gk ^ ((rb_ >> 1) & 3)) * 16));        \
        }

#define MFMA16(fh)                                                             \
        __builtin_amdgcn_s_setprio(1);                                         \
        _Pragma("unroll")                                                      \
        for (int i = 0; i < 4; ++i)                                           \
            _Pragma("unroll")                                                  \
            for (int j = 0; j < 4; ++j)                                       \
                acc[(fh) * 4 + i][j] = __builtin_amdgcn_mfma_i32_16x16x64_i8( \
                    a_[i], bfrag[j], acc[(fh) * 4 + i][j], 0, 0, 0);          \
        __builtin_amdgcn_s_setprio(0);

    // fh=0 phase: read A-quadrant + B (new kh), then MFMA
#define PHASE_AB(bufA, bufB, kh, STAGE_STMT, WAIT_STMT)                        \
    {                                                                          \
        i32x4 a_[4];                                                           \
        READ_A(bufA, 0, kh);                                                   \
        READ_B(bufB, kh);                                                      \
        STAGE_STMT;                                                            \
        __builtin_amdgcn_s_barrier();                                          \
        MFMA16(0);                                                             \
        WAIT_STMT;                                                             \
        __builtin_amdgcn_s_barrier();                                          \
    }

    // fh=1 phase: read A-quadrant only, reuse bfrag (registers, barrier-safe)
#define PHASE_A(bufA, kh, STAGE_STMT, WAIT_STMT)                               \
    {                                                                          \
        i32x4 a_[4];                                                           \
        READ_A(bufA, 1, kh);                                                   \
        STAGE_STMT;                                                            \
        __builtin_amdgcn_s_barrier();                                          \
        MFMA16(1);                                                             \
        WAIT_STMT;                                                             \
        __builtin_amdgcn_s_barrier();                                          \
    }

#define KTILE(buf, S1, S2, S3, S4, W2, W4)                                     \
    PHASE_AB((buf) * 32768, 65536 + (buf) * 32768, 0, S1, NOWAIT);            \
    PHASE_A ((buf) * 32768, 0, S2, W2);                                       \
    PHASE_AB((buf) * 32768, 65536 + (buf) * 32768, 1, S3, NOWAIT);            \
    PHASE_A ((buf) * 32768, 1, S4, W4);

    // ---- prologue: Klo(0),Khi(0) -> buf0; Klo(1) -> buf1 ----
    STAGE_HALF(gA, 0,   0, 0);
    STAGE_HALF(gB, 0,   0, 65536);
    STAGE_HALF(gA, 0,   1, 0);
    STAGE_HALF(gB, 0,   1, 65536);
    STAGE_HALF(gA, BKB, 0, 32768);
    STAGE_HALF(gB, BKB, 0, 65536 + 32768);
    VM4;                                   // allow Klo(1) pair outstanding
    __builtin_amdgcn_s_barrier();

    // ---- main loop: tiles 0..29, static buffer parity ----
    for (int t = 0; t < NT - 2; t += 2) {
        KTILE(0,
              STAGE_HALF(gA, (t + 1) * BKB, 1, 32768),
              STAGE_HALF(gB, (t + 1) * BKB, 1, 65536 + 32768),
              STAGE_HALF(gA, (t + 2) * BKB, 0, 0),
              STAGE_HALF(gB, (t + 2) * BKB, 0, 65536),
              VM8, VM8);
        KTILE(1,
              STAGE_HALF(gA, (t + 2) * BKB, 1, 0),
              STAGE_HALF(gB, (t + 2) * BKB, 1, 65536),
              STAGE_HALF(gA, (t + 3) * BKB, 0, 32768),
              STAGE_HALF(gB, (t + 3) * BKB, 0, 65536 + 32768),
              VM8, VM8);
    }
    // ---- tile 30 (buf0): stage only Khi(31) -> buf1 ----
    KTILE(0,
          STAGE_HALF(gA, 31 * BKB, 1, 32768),
          STAGE_HALF(gB, 31 * BKB, 1, 65536 + 32768),
          NOSTAGE, NOSTAGE,
          VM8, VM4);
    // ---- tile 31 (buf1): no stages; drain Khi(31) before p3 ----
    KTILE(1, NOSTAGE, NOSTAGE, NOSTAGE, NOSTAGE, VM0, NOWAIT);

#undef KTILE
#undef PHASE_A
#undef PHASE_AB
#undef MFMA16
#undef READ_B
#undef READ_A
#undef STAGE_HALF

    // ---- epilogue: y = acc * (s[m]*wscale) + bias[n] ----
    // C/D layout: col = lane&15, row = (lane>>4)*4 + reg (dtype-independent)
    const float ws = wsc[0];
    float bs[4];
#pragma unroll
    for (int j = 0; j < 4; ++j) bs[j] = bias[bn + wc * 64 + j * 16 + fr];

#pragma unroll
    for (int i = 0; i < 8; ++i) {
        const int m0 = bm + wr * 128 + i * 16 + gk * 4;
#pragma unroll
        for (int r = 0; r < 4; ++r) {
            const float sm = srow[m0 + r] * ws;
            float* yp = Y + (size_t)(m0 + r) * D_OUT + bn + wc * 64 + fr;
#pragma unroll
            for (int j = 0; j < 4; ++j)
                yp[j * 16] = (float)acc[i][j][r] * sm + bs[j];
        }
    }
}

// ---------------------------------------------------------------------------
extern "C" void kernel_launch(void* const* d_in, const int* in_sizes, int n_in,
                              void* d_out, int out_size, void* d_ws, size_t ws_size,
                              hipStream_t stream) {
    const float* x    = (const float*)d_in[0];
    const int*   w32  = (const int*)d_in[1];     // int8 values widened to int32
    const float* wsc  = (const float*)d_in[2];
    const float* bias = (const float*)d_in[3];
    float* y = (float*)d_out;

    // workspace layout: qx (32 MiB) | w8 (16 MiB) | s (32 KiB)
    int8_t* xq = (int8_t*)d_ws;
    int8_t* w8 = xq + (size_t)M_TOT * D_IN;
    float*  s  = (float*)(w8 + (size_t)D_OUT * D_IN);

    const int pack_blocks = (D_OUT * D_IN / 4) / 256;   // 16384
    prep<<<M_TOT + pack_blocks, 256, 0, stream>>>(x, xq, s, w32, w8);

    gemm_i8<<<(M_TOT / BM) * (D_OUT / BN), 512, 0, stream>>>(xq, w8, s, wsc, bias, y);
}